// Round 7
// baseline (246.083 us; speedup 1.0000x reference)
//
#include <hip/hip_runtime.h>

#define HEADS 32
#define DK    64
#define NSEQ  2048
#define BATCH 2
#define DIN   512
#define INNER 2048  // HEADS*DK

typedef float f32x2 __attribute__((ext_vector_type(2)));
typedef float f32x4 __attribute__((ext_vector_type(4)));
typedef float f32x16 __attribute__((ext_vector_type(16)));
typedef short s16x8 __attribute__((ext_vector_type(8)));
typedef short s16x4 __attribute__((ext_vector_type(4)));
typedef unsigned u32x2 __attribute__((ext_vector_type(2)));
typedef unsigned u32x4 __attribute__((ext_vector_type(4)));

#define AS1 __attribute__((address_space(1)))
#define AS3 __attribute__((address_space(3)))

__device__ __forceinline__ short f2b(float f) {
  unsigned u = __float_as_uint(f);
  u += 0x7fffu + ((u >> 16) & 1u);   // round-to-nearest-even
  return (short)(u >> 16);
}

__device__ __forceinline__ unsigned cvt_pk_bf16(float lo, float hi) {
  unsigned r;
  asm("v_cvt_pk_bf16_f32 %0, %1, %2" : "=v"(r) : "v"(lo), "v"(hi));
  return r;
}

// cross-half (lane ^ 32) max / add via permlane32_swap (full-rate VALU, no LDS)
__device__ __forceinline__ float xhalf_max(float v) {
  u32x2 r = __builtin_amdgcn_permlane32_swap(__float_as_uint(v), __float_as_uint(v),
                                             false, false);
  return fmaxf(__uint_as_float(r[0]), __uint_as_float(r[1]));
}
__device__ __forceinline__ float xhalf_add(float v) {
  u32x2 r = __builtin_amdgcn_permlane32_swap(__float_as_uint(v), __float_as_uint(v),
                                             false, false);
  return __uint_as_float(r[0]) + __uint_as_float(r[1]);
}

// async global->LDS, 16B per lane; lds dest = wave-uniform base + lane*16
__device__ __forceinline__ void gll16(const short* gp, short* lp) {
  __builtin_amdgcn_global_load_lds((const AS1 unsigned*)gp, (AS3 unsigned*)lp, 16, 0, 0);
}

// A-frag-linear (16x16x32 A operand), unit = 16 rows x 32 k = 512 shorts:
//   lin = (m>>4)*(K*16) + (k>>5)*512 + (m&15)*8 + ((k>>3)&3)*128 + (k&7)
// B-frag-linear identical with n in place of m.
// Q/K attn layout per (b,h): lin = (n>>5)*2048 + (dk>>4)*512 + ((dk>>3)&1)*256 + (n&31)*8 + (dk&7)
// V  attn layout per (b,h): lin = (n>>5)*2048 + ((n>>4)&1)*1024 + (dk>>5)*512 + ((n>>3)&1)*256 + (dk&31)*8 + (n&7)

// ---------- convert x: f32 [4096][512] -> bf16 A-frag-linear ----------
__global__ __launch_bounds__(256) void k_cvt(const float* __restrict__ in,
                                             short* __restrict__ out) {
  int t = blockIdx.x * 256 + threadIdx.x;    // 262144 threads, one 16B chunk each
  int m = t >> 6, kc = t & 63;               // kc: 8-elem chunk within row
  const float* src = in + (size_t)m * 512 + kc * 8;
  float4 v0 = *reinterpret_cast<const float4*>(src);
  float4 v1 = *reinterpret_cast<const float4*>(src + 4);
  s16x8 o;
  o[0] = f2b(v0.x); o[1] = f2b(v0.y); o[2] = f2b(v0.z); o[3] = f2b(v0.w);
  o[4] = f2b(v1.x); o[5] = f2b(v1.y); o[6] = f2b(v1.z); o[7] = f2b(v1.w);
  size_t lin = (size_t)(m >> 4) * 8192 + (kc >> 2) * 512 + (kc & 3) * 128 + (m & 15) * 8;
  *reinterpret_cast<s16x8*>(out + lin) = o;
}

// ---- transpose W [R][C] f32 -> out B-frag-linear over (n=C-dim, k=R-dim) ----
__global__ __launch_bounds__(256) void k_transpose(const float* __restrict__ in,
                                                   short* __restrict__ out,
                                                   int R, int C) {
  __shared__ float tile[64][65];
  const int tc = blockIdx.x * 64;
  const int tr = blockIdx.y * 64;
  const int tx = threadIdx.x & 63;
  const int ty = threadIdx.x >> 6;
#pragma unroll
  for (int rr = ty; rr < 64; rr += 4)
    tile[rr][tx] = in[(size_t)(tr + rr) * C + tc + tx];
  __syncthreads();
#pragma unroll
  for (int rr = ty; rr < 64; rr += 4) {
    int n = tc + rr, k = tr + tx;
    size_t lin = (size_t)(n >> 4) * ((size_t)R * 16) + (k >> 5) * 512 +
                 ((k >> 3) & 3) * 128 + (n & 15) * 8 + (k & 7);
    out[lin] = f2b(tile[tx][rr]);
  }
}

// -------- fused QKV projection GEMM: M=4096, N=6144, K=512 --------
// 128x128 block tile, 4 waves of 64x64, BK=32, double-buffered LDS (T3 2-phase).
__global__ __launch_bounds__(256) void k_gemm_qkv(const short* __restrict__ A,
                                                  const short* __restrict__ Bw,
                                                  short* __restrict__ Qb,
                                                  short* __restrict__ Kb,
                                                  short* __restrict__ Vb) {
  __shared__ short sA[2][4096];   // 8 KB per buffer: 8 units of 512
  __shared__ short sB[2][4096];
  const int bm = blockIdx.x * 128;
  const int bn = blockIdx.y * 128;
  const int wave = threadIdx.x >> 6, lane = threadIdx.x & 63;
  const int l16 = lane & 15, g = lane >> 4;
  const int wr = wave >> 1, wc = wave & 1;

  const short* Au = A + ((size_t)(bm >> 4) + wave) * 8192 + lane * 8;   // K=512: unit stride 8192
  const short* Bu = Bw + ((size_t)(bn >> 4) + wave) * 8192 + lane * 8;

  f32x4 acc[4][4] = {};

  auto stage = [&](int buf, int kt) {
    gll16(Au + kt * 512,              &sA[buf][wave * 512]);
    gll16(Au + 4 * 8192 + kt * 512,   &sA[buf][(wave + 4) * 512]);
    gll16(Bu + kt * 512,              &sB[buf][wave * 512]);
    gll16(Bu + 4 * 8192 + kt * 512,   &sB[buf][(wave + 4) * 512]);
  };

  stage(0, 0);
  __syncthreads();                       // implicit vmcnt(0): buf0 ready
  int cur = 0;
  for (int kt = 0; kt < 16; ++kt) {
    if (kt + 1 < 16) stage(cur ^ 1, kt + 1);
    s16x8 a[4], b[4];
#pragma unroll
    for (int i = 0; i < 4; i++)
      a[i] = *reinterpret_cast<const s16x8*>(&sA[cur][(wr * 4 + i) * 512 + lane * 8]);
#pragma unroll
    for (int c = 0; c < 4; c++)
      b[c] = *reinterpret_cast<const s16x8*>(&sB[cur][(wc * 4 + c) * 512 + lane * 8]);
#pragma unroll
    for (int i = 0; i < 4; i++)
#pragma unroll
      for (int c = 0; c < 4; c++)
        acc[i][c] = __builtin_amdgcn_mfma_f32_16x16x32_bf16(a[i], b[c], acc[i][c], 0, 0, 0);
    if (kt + 1 < 16) { __syncthreads(); cur ^= 1; }   // drains vmcnt+lgkm: safe swap
  }

  const int proj = bn >> 11;             // 0=Q 1=K 2=V (block-uniform)
#pragma unroll
  for (int i = 0; i < 4; i++)
#pragma unroll
    for (int c = 0; c < 4; c++)
#pragma unroll
      for (int r = 0; r < 4; r++) {
        int row = bm + wr * 64 + i * 16 + 4 * g + r;      // token
        int col = bn + wc * 64 + c * 16 + l16;
        float v = acc[i][c][r];
        int b = row >> 11, n = row & 2047;
        int nc = col & 2047;
        int h = nc >> 6, dk = nc & 63;
        size_t hb = (size_t)(b * HEADS + h) * (NSEQ * DK);
        if (proj == 2) {
          size_t idx = hb + (size_t)(n >> 5) * 2048 + ((n >> 4) & 1) * 1024 +
                       (dk >> 5) * 512 + ((n >> 3) & 1) * 256 + (dk & 31) * 8 + (n & 7);
          Vb[idx] = f2b(v);
        } else {
          size_t idx = hb + (size_t)(n >> 5) * 2048 + (dk >> 4) * 512 +
                       ((dk >> 3) & 1) * 256 + (n & 31) * 8 + (dk & 7);
          if (proj == 0) Qb[idx] = f2b(v * 0.18033688f);  // 0.125*log2(e)
          else           Kb[idx] = f2b(v);
        }
      }
}

// -------- output projection GEMM: M=4096, N=512, K=2048, f32 out + bias --------
// 64x128 block tile, 2 waves of 64x64, BK=32, double-buffered LDS.
__global__ __launch_bounds__(128) void k_gemm_out(const short* __restrict__ A,
                                                  const short* __restrict__ Bw,
                                                  float* __restrict__ out,
                                                  const float* __restrict__ bias) {
  __shared__ short sA[2][2048];   // 4 KB per buffer: 4 units
  __shared__ short sB[2][4096];   // 8 KB per buffer: 8 units
  const int bm = blockIdx.x * 64;
  const int bn = blockIdx.y * 128;
  const int wave = threadIdx.x >> 6, lane = threadIdx.x & 63;
  const int l16 = lane & 15, g = lane >> 4;

  const short* Au = A + ((size_t)(bm >> 4)) * 32768 + lane * 8;   // K=2048: unit stride 32768
  const short* Bu = Bw + ((size_t)(bn >> 4)) * 32768 + lane * 8;

  f32x4 acc[4][4] = {};

  auto stage = [&](int buf, int kt) {
    gll16(Au + (size_t)(2 * wave + 0) * 32768 + kt * 512, &sA[buf][(2 * wave + 0) * 512]);
    gll16(Au + (size_t)(2 * wave + 1) * 32768 + kt * 512, &sA[buf][(2 * wave + 1) * 512]);
#pragma unroll
    for (int j = 0; j < 4; j++)
      gll16(Bu + (size_t)(4 * wave + j) * 32768 + kt * 512, &sB[buf][(4 * wave + j) * 512]);
  };

  stage(0, 0);
  __syncthreads();
  int cur = 0;
  for (int kt = 0; kt < 64; ++kt) {
    if (kt + 1 < 64) stage(cur ^ 1, kt + 1);
    s16x8 a[4], b[4];
#pragma unroll
    for (int i = 0; i < 4; i++)
      a[i] = *reinterpret_cast<const s16x8*>(&sA[cur][i * 512 + lane * 8]);
#pragma unroll
    for (int c = 0; c < 4; c++)
      b[c] = *reinterpret_cast<const s16x8*>(&sB[cur][(wave * 4 + c) * 512 + lane * 8]);
#pragma unroll
    for (int i = 0; i < 4; i++)
#pragma unroll
      for (int c = 0; c < 4; c++)
        acc[i][c] = __builtin_amdgcn_mfma_f32_16x16x32_bf16(a[i], b[c], acc[i][c], 0, 0, 0);
    if (kt + 1 < 64) { __syncthreads(); cur ^= 1; }
  }

#pragma unroll
  for (int i = 0; i < 4; i++)
#pragma unroll
    for (int c = 0; c < 4; c++)
#pragma unroll
      for (int r = 0; r < 4; r++) {
        int row = bm + i * 16 + 4 * g + r;
        int col = bn + wave * 64 + c * 16 + l16;
        out[(size_t)row * 512 + col] = acc[i][c][r] + bias[col];
      }
}

// ---------------- flash attention, swapped-QK^T in-register softmax ----------
// Q (pre-scaled by 0.125*log2e), K, V in attn fragment-linear layouts.
// att out: A-frag-linear over (mrow = b*2048+q, hd = h*64+dk), unit stride 32768.
// 1-D grid 2048, XCD-swizzled: xcd = bid&7 owns 8 (b,h) groups, group-major.
// Pipeline: QK(t+1) issues after softmax(t)'s cvt (st regs dead), before PV(t).
__global__ __launch_bounds__(128) void k_attn(const short* __restrict__ Q,
                                              const short* __restrict__ K,
                                              const short* __restrict__ VT,
                                              short* __restrict__ att) {
  const int wave = threadIdx.x >> 6, lane = threadIdx.x & 63;
  const int l32 = lane & 31, hi = lane >> 5;
  // XCD-aware decode: blocks with bid%8==k all serve heads g in [8k, 8k+8)
  const int bid = blockIdx.x;
  const int xcd = bid & 7, slot = bid >> 3;      // slot 0..255
  const int g = xcd * 8 + (slot >> 5);           // (b,h) group 0..63
  const int qt = slot & 31;                      // q-tile (64 rows)
  const int h = g & 31, b = g >> 5;
  const int q0 = qt * 64 + wave * 32;
  const size_t hb = ((size_t)b * HEADS + h) * (size_t)NSEQ * DK;
  const short* Qh = Q + hb;
  const short* Kh = K + hb;
  const short* Vh = VT + hb;

  // Q B-frags: fully coalesced, base + lane*16B
  s16x8 qf[4];
  {
    const short* qbase = Qh + (size_t)(q0 >> 5) * 2048 + lane * 8;
#pragma unroll
    for (int c = 0; c < 4; c++) qf[c] = *reinterpret_cast<const s16x8*>(qbase + c * 512);
  }

  f32x16 ot[2] = {};              // O^T accum: d-tiles 0/1, col=q, row=d
  float m = -1e30f, lsum = 0.f;

  constexpr int NT = NSEQ / 32;
  s16x8 kA[4], kB[4];
  f32x16 st;
  {
    const short* kbase = Kh + lane * 8;          // K(0)
#pragma unroll
    for (int c = 0; c < 4; c++) kA[c] = *reinterpret_cast<const s16x8*>(kbase + c * 512);
    f32x16 z = {};
#pragma unroll
    for (int c = 0; c < 4; c++)
      z = __builtin_amdgcn_mfma_f32_32x32x16_bf16(kA[c], qf[c], z, 0, 0, 0);
    st = z;                                       // scores(0)
    const short* kbase1 = Kh + 2048 + lane * 8;   // K(1)
#pragma unroll
    for (int c = 0; c < 4; c++) kB[c] = *reinterpret_cast<const s16x8*>(kbase1 + c * 512);
  }

  // body(t): st holds scores(t); ku = K(t+1); kl <- K(t+2)
  auto body = [&](s16x8(&ku)[4], s16x8(&kl)[4], int t) {
    // V A-frags (independent -> issue first)
    const short* vbase = Vh + (size_t)t * 2048 + lane * 8;
    s16x8 vf00 = *reinterpret_cast<const s16x8*>(vbase);         // ks0, dt0
    s16x8 vf01 = *reinterpret_cast<const s16x8*>(vbase + 512);   // ks0, dt1
    s16x8 vf10 = *reinterpret_cast<const s16x8*>(vbase + 1024);  // ks1, dt0
    s16x8 vf11 = *reinterpret_cast<const s16x8*>(vbase + 1536);  // ks1, dt1

    // prefetch K(t+2) into kl (clamped, branchless)
    int tn = (t + 2 < NT) ? t + 2 : t;
    const short* kbase = Kh + (size_t)tn * 2048 + lane * 8;
#pragma unroll
    for (int c = 0; c < 4; c++) kl[c] = *reinterpret_cast<const s16x8*>(kbase + c * 512);

    // ---- online softmax on st, lane-local (v_max3-friendly triples) ----
    float u0 = fmaxf(fmaxf(st[0], st[1]), st[2]);
    float u1 = fmaxf(fmaxf(st[3], st[4]), st[5]);
    float u2 = fmaxf(fmaxf(st[6], st[7]), st[8]);
    float u3 = fmaxf(fmaxf(st[9], st[10]), st[11]);
    float u4 = fmaxf(fmaxf(st[12], st[13]), st[14]);
    float mx = fmaxf(fmaxf(fmaxf(u0, u1), u2), fmaxf(fmaxf(u3, u4), st[15]));
    mx = xhalf_max(mx);

    if (!__all(mx <= m + 11.5f)) {   // defer-max (T13), log2 units
      float mnew = fmaxf(m, mx);
      float alpha = __builtin_amdgcn_exp2f(m - mnew);
      lsum *= alpha;
#pragma unroll
      for (int r = 0; r < 16; r++) { ot[0][r] *= alpha; ot[1][r] *= alpha; }
      m = mnew;
    }

    // exp2 in place: st regs become p
#pragma unroll
    for (int r = 0; r < 16; r++) st[r] = __builtin_amdgcn_exp2f(st[r] - m);

    // row sum via packed f32 adds
    f32x2 e0 = (f32x2){st[0], st[1]} + (f32x2){st[2], st[3]};
    f32x2 e1 = (f32x2){st[4], st[5]} + (f32x2){st[6], st[7]};
    f32x2 e2 = (f32x2){st[8], st[9]} + (f32x2){st[10], st[11]};
    f32x2 e3 = (f32x2){st[12], st[13]} + (f32x2){st[14], st[15]};
    e0 += e1; e2 += e3; e0 += e2;
    lsum += xhalf_add(e0[0] + e0[1]);

    // ---- P^T B-frag build: cvt_pk pairs + permlane32_swap (T12) ----
    unsigned a0 = cvt_pk_bf16(st[0], st[1]),   a1 = cvt_pk_bf16(st[2], st[3]);
    unsigned a2 = cvt_pk_bf16(st[4], st[5]),   a3 = cvt_pk_bf16(st[6], st[7]);
    unsigned a4 = cvt_pk_bf16(st[8], st[9]),   a5 = cvt_pk_bf16(st[10], st[11]);
    unsigned a6 = cvt_pk_bf16(st[12], st[13]), a7 = cvt_pk_bf16(st[14], st[15]);
    u32x2 w0 = __builtin_amdgcn_permlane32_swap(a0, a2, false, false);
    u32x2 w1 = __builtin_amdgcn_permlane32_swap(a1, a3, false, false);
    u32x2 w2 = __builtin_amdgcn_permlane32_swap(a4, a6, false, false);
    u32x2 w3 = __builtin_amdgcn_permlane32_swap(a5, a7, false, false);
    u32x4 pw0 = {w0[0], w1[0], w0[1], w1[1]};
    u32x4 pw1 = {w2[0], w3[0], w2[1], w3[1]};
    s16x8 pf0 = __builtin_bit_cast(s16x8, pw0);
    s16x8 pf1 = __builtin_bit_cast(s16x8, pw1);

    // QK(t+1) into st (st regs dead after cvt) — overlaps next softmax's wait
    if (t + 1 < NT) {
      f32x16 z = {};
#pragma unroll
      for (int c = 0; c < 4; c++)
        z = __builtin_amdgcn_mfma_f32_32x32x16_bf16(ku[c], qf[c], z, 0, 0, 0);
      st = z;
    }

    // O^T += V^T . P^T
    ot[0] = __builtin_amdgcn_mfma_f32_32x32x16_bf16(vf00, pf0, ot[0], 0, 0, 0);
    ot[1] = __builtin_amdgcn_mfma_f32_32x32x16_bf16(vf01, pf0, ot[1], 0, 0, 0);
    ot[0] = __builtin_amdgcn_mfma_f32_32x32x16_bf16(vf10, pf1, ot[0], 0, 0, 0);
    ot[1] = __builtin_amdgcn_mfma_f32_32x32x16_bf16(vf11, pf1, ot[1], 0, 0, 0);
  };

  for (int t = 0; t < NT; t += 2) {
    body(kB, kA, t);       // uses K(t+1)=kB, loads K(t+2)->kA
    body(kA, kB, t + 1);   // uses K(t+2)=kA, loads K(t+3)->kB
  }

  // epilogue: normalize + write att in A-frag-linear (unit stride 32768, K=2048)
  float inv = 1.f / lsum;
  size_t aunit = ((size_t)(b * 128) + (size_t)((q0 + l32) >> 4)) * 32768;
  const int mr = l32 & 15;
#pragma unroll
  for (int dt = 0; dt < 2; dt++)
#pragma unroll
    for (int gq = 0; gq < 4; gq++) {
      s16x4 w;
#pragma unroll
      for (int j = 0; j < 4; j++) w[j] = f2b(ot[dt][4 * gq + j] * inv);
      size_t base = aunit + (size_t)(h * 2 + dt) * 512 + gq * 128 + mr * 8 + 4 * hi;
      *reinterpret_cast<s16x4*>(att + base) = w;
    }
}

extern "C" void kernel_launch(void* const* d_in, const int* in_sizes, int n_in,
                              void* d_out, int out_size, void* d_ws, size_t ws_size,
                              hipStream_t stream) {
  const float* x  = (const float*)d_in[0];
  const float* Wq = (const float*)d_in[1];
  const float* Wk = (const float*)d_in[2];
  const float* Wv = (const float*)d_in[3];
  const float* Wz = (const float*)d_in[4];
  const float* bz = (const float*)d_in[5];

  char* ws = (char*)d_ws;
  const size_t MB = (size_t)1 << 20;
  short* xb   = (short*)(ws);             // A-frag-linear x    4 MB
  short* wqkv = (short*)(ws + 4 * MB);    // B-frag-linear QKV  6 MB
  short* wzt  = (short*)(ws + 10 * MB);   // B-frag-linear Wz   2 MB
  short* Qb   = (short*)(ws + 12 * MB);   // attn Q layout     16 MB
  short* Kb   = (short*)(ws + 28 * MB);   // attn K layout     16 MB
  short* Vt   = (short*)(ws + 44 * MB);   // attn V layout     16 MB
  short* att  = (short*)(ws + 60 * MB);   // A-frag-linear att 16 MB

  k_cvt<<<1024, 256, 0, stream>>>(x, xb);
  k_transpose<<<dim3(32, 8), 256, 0, stream>>>(Wq, wqkv,               DIN, INNER);
  k_transpose<<<dim3(32, 8), 256, 0, stream>>>(Wk, wqkv + 1048576,     DIN, INNER);
  k_transpose<<<dim3(32, 8), 256, 0, stream>>>(Wv, wqkv + 2097152,     DIN, INNER);
  k_transpose<<<dim3(8, 32), 256, 0, stream>>>(Wz, wzt,                INNER, DIN);

  k_gemm_qkv<<<dim3(32, 48), 256, 0, stream>>>(xb, wqkv, Qb, Kb, Vt);

  k_attn<<<2048, 128, 0, stream>>>(Qb, Kb, Vt, att);

  k_gemm_out<<<dim3(64, 4), 128, 0, stream>>>(att, wzt, (float*)d_out, bz);
}